// Round 13
// baseline (80.399 us; speedup 1.0000x reference)
//
#include <hip/hip_runtime.h>
#include <hip/hip_fp16.h>

typedef _Float16 f16x8 __attribute__((ext_vector_type(8)));
typedef _Float16 f16x4 __attribute__((ext_vector_type(4)));
typedef _Float16 f16x2 __attribute__((ext_vector_type(2)));
typedef float    f32x4 __attribute__((ext_vector_type(4)));

#define BM 128    // one 128-row block per CU, 12 waves, full 153.6 KB LDS

// layer geometry (h=0 => only first IN rows of each weight matter; the
// padded K range includes a bias row at k==IN carrying 1.0 in activations)
#define IN0 74
#define H0  269
#define H1  179
#define H2  64
#define KS0 3     // ceil((IN0+1)/32)
#define KS1 9     // ceil((H0+1)/32)
#define KS2 6     // ceil((H1+1)/32)
#define NP0 288   // H0 padded to mult of 32 (tile-PAIRS of 16)
#define NP1 192
#define NP2 64
#define PX  104   // LDS row pitches (halfs): odd multiples of 16B -> spread banks
#define PH0 296
#define PH1 200
#define WPB 12    // waves per block

// SWAPPED operands: weights as the A-matrix, activations as B.
// C/D layout: col(lane&15)=batch row, row(lg*4+q)=feature -> each lane's 4
// outputs are 4 CONSECUTIVE features of one batch row.
#define MFMA16(a, b, c) __builtin_amdgcn_mfma_f32_16x16x32_f16(a, b, c, 0, 0, 0)

// THREE matrices per layer: m0 = 2*mask*Wf1 (+2*bf1 bias row),
// m1 = 2*mask*Wf2 (+2*bf2), m2 = Wtb - Wta (+ btb - bta); the time gate
// needs only the difference. tanh via r = 1/(1+exp(acc)): tanh = 1-2r.
__device__ __forceinline__ float rform(float y) {
  return __builtin_amdgcn_rcpf(1.f + __expf(y));
}

// One CfC layer for this block's 128 rows. 12 waves iterate flat work-units
// u = (feature tile-PAIR p = u/G, row-group u%G of S*16 rows). Per unit ONE
// K-sweep accumulating 3 mats x 2 feature-tiles (acc[3][2][S] = 96 AGPRs,
// needs the 170-reg/wave budget of __launch_bounds__(768,3)): each LDS
// act-read feeds 6 MFMAs (halves LDS traffic vs single-tile units), and
// 64-row units halve per-row weight re-reads. B loads are just-in-time in a
// FORCIBLY ROLLED ks loop (TLP across 3 waves/SIMD hides L2 latency; a
// rolling window would blow the register budget).
// Epilogue: r1,r2 = rform(acc0/1), ti = rform(-acc2) = sigmoid(tb-ta),
// o = 1 - 2*(r1 - ti*(r1-r2)); packed f16x4 LDS write / float4 global.
template<int KS, int NP, int HID, int IPITCH, int OPITCH, bool LAST, int S, int G>
__device__ __forceinline__ void layer_run(
    const _Float16* in_lds, _Float16* out_lds, float* out_g,
    const _Float16* __restrict__ wt, int lane, int wid)
{
  constexpr int NPR = NP / 32;    // feature tile-pairs
  const int l15 = lane & 15;
  const int lg  = lane >> 4;
  #pragma unroll 1
  for (int u = wid; u < NPR * G; u += WPB) {
    const int p     = u / G;
    const int mbase = (u % G) * (S * 16);
    const _Float16* a_base = in_lds + (mbase + l15) * IPITCH + lg * 8;
    const _Float16* w0 = wt + (size_t)(2 * p * KS * 3) * 512 + lane * 8;
    const _Float16* w1 = w0 + (size_t)(KS * 3) * 512;

    f32x4 acc[3][2][S] = {};
    #pragma unroll 1
    for (int ks = 0; ks < KS; ++ks) {
      const _Float16* k0p = w0 + (size_t)ks * 1536;
      const _Float16* k1p = w1 + (size_t)ks * 1536;
      f16x8 b00 = *(const f16x8*)(k0p);
      f16x8 b01 = *(const f16x8*)(k0p + 512);
      f16x8 b02 = *(const f16x8*)(k0p + 1024);
      f16x8 b10 = *(const f16x8*)(k1p);
      f16x8 b11 = *(const f16x8*)(k1p + 512);
      f16x8 b12 = *(const f16x8*)(k1p + 1024);
      #pragma unroll
      for (int s = 0; s < S; ++s) {
        f16x8 a = *(const f16x8*)(a_base + s * 16 * IPITCH + ks * 32);
        acc[0][0][s] = MFMA16(b00, a, acc[0][0][s]);
        acc[1][0][s] = MFMA16(b01, a, acc[1][0][s]);
        acc[2][0][s] = MFMA16(b02, a, acc[2][0][s]);
        acc[0][1][s] = MFMA16(b10, a, acc[0][1][s]);
        acc[1][1][s] = MFMA16(b11, a, acc[1][1][s]);
        acc[2][1][s] = MFMA16(b12, a, acc[2][1][s]);
      }
    }

    // epilogue: per (tile nt, s), lane owns batch row m, 4 consecutive feats
    #pragma unroll
    for (int nt = 0; nt < 2; ++nt) {
      const int nb = (2 * p + nt) * 16 + lg * 4;
      #pragma unroll
      for (int s = 0; s < S; ++s) {
        const int m = mbase + s * 16 + l15;
        float o[4];
        #pragma unroll
        for (int q = 0; q < 4; ++q) {
          float r1 = rform(acc[0][nt][s][q]);        // acc0 = 2*f1
          float r2 = rform(acc[1][nt][s][q]);        // acc1 = 2*f2
          float ti = rform(-acc[2][nt][s][q]);       // sigmoid(tb-ta)
          o[q] = 1.f - 2.f * (r1 - ti * (r1 - r2));
        }
        if (LAST) {
          float4 v = make_float4(o[0], o[1], o[2], o[3]);
          *(float4*)(out_g + m * 64 + nb) = v;       // NP2==H2, no guard
        } else if (nb + 4 <= HID) {
          f16x4 h = {(_Float16)o[0], (_Float16)o[1], (_Float16)o[2], (_Float16)o[3]};
          *(f16x4*)(out_lds + m * OPITCH + nb) = h;  // one b64 write
        } else {
          #pragma unroll
          for (int q = 0; q < 4; ++q)
            if (nb + q < HID) out_lds[m * OPITCH + nb + q] = (_Float16)o[q];
        }
      }
    }
  }
}

__global__ __launch_bounds__(768, 3) void cfc_fused(
    const float* __restrict__ x,
    const _Float16* __restrict__ wt0, const _Float16* __restrict__ wt1,
    const _Float16* __restrict__ wt2,
    float* __restrict__ out)
{
  __shared__ __align__(16) _Float16 xs [BM * PX];   // 26624 B
  __shared__ __align__(16) _Float16 h0s[BM * PH0];  // 75776 B
  __shared__ __align__(16) _Float16 h1s[BM * PH1];  // 51200 B -> 153600 total
  const int tid  = threadIdx.x;
  const int lane = tid & 63;
  const int wid  = tid >> 6;
  const int m0 = blockIdx.x * BM;

  // pad columns: 1.0 at the bias slot k==IN, 0 elsewhere in [IN, KP)
  for (int i = tid; i < BM * 22; i += 768) { int r = i / 22, c = IN0 + i - r * 22; xs [r * PX  + c] = (_Float16)(c == IN0 ? 1.f : 0.f); }
  for (int i = tid; i < BM * 19; i += 768) { int r = i / 19, c = H0  + i - r * 19; h0s[r * PH0 + c] = (_Float16)(c == H0  ? 1.f : 0.f); }
  for (int i = tid; i < BM * 13; i += 768) { int r = i / 13, c = H1  + i - r * 13; h1s[r * PH1 + c] = (_Float16)(c == H1  ? 1.f : 0.f); }

  // stage x (fp32 -> fp16) into LDS, float2 loads, packed b32 LDS writes
  for (int i = tid; i < BM * 37; i += 768) {
    int r = i / 37, p = i - r * 37;
    float2 v = ((const float2*)x)[(size_t)(m0 + r) * 37 + p];
    f16x2 hv = {(_Float16)v.x, (_Float16)v.y};
    *(f16x2*)(xs + r * PX + 2 * p) = hv;
  }
  __syncthreads();

  layer_run<KS0, NP0, H0, PX,  PH0, false, 4, 2>(xs,  h0s, nullptr, wt0, lane, wid);
  __syncthreads();
  layer_run<KS1, NP1, H1, PH0, PH1, false, 4, 2>(h0s, h1s, nullptr, wt1, lane, wid);
  __syncthreads();
  layer_run<KS2, NP2, H2, PH1, 1,   true,  2, 4>(h1s, nullptr, out + (size_t)m0 * 64,
                                                 wt2, lane, wid);
}

// Pack weights into fragment-major order, 3 matrices per layer.
// One thread per (chunk, lane): chunk c = (t*KS + ks)*3 + m, halfs j:
// k = ks*32+(lane>>4)*8+j, n = t*16+(lane&15).
// m=0: 2*mask*Wf1 (bias row 2*bf1); m=1: 2*mask*Wf2 (2*bf2);
// m=2: Wtb - Wta (bias row btb - bta). Zero outside [0,IN] x [0,HID).
__global__ void pack_w(const float* __restrict__ wf1, const float* __restrict__ wf2,
                       const float* __restrict__ wta, const float* __restrict__ wtb,
                       const float* __restrict__ bf1, const float* __restrict__ bf2,
                       const float* __restrict__ bta, const float* __restrict__ btb,
                       const int* __restrict__ mask, _Float16* __restrict__ wt,
                       int IN, int HID, int KS, int NT)
{
  int idx = blockIdx.x * 256 + threadIdx.x;
  int total = NT * KS * 3 * 64;
  if (idx >= total) return;
  int lane = idx & 63;
  int c = idx >> 6;          // chunk = (t*KS + ks)*3 + m
  int m = c % 3;
  int tk = c / 3;
  int ks = tk % KS;
  int t  = tk / KS;
  int n  = t * 16 + (lane & 15);
  int k0 = ks * 32 + (lane >> 4) * 8;
  f16x8 v = {};
  if (n < HID) {
    #pragma unroll
    for (int j = 0; j < 8; ++j) {
      int k = k0 + j;
      float f = 0.f;
      if (k < IN) {
        if (m == 0)      f = 2.f * wf1[k * HID + n] * (float)mask[k * HID + n];
        else if (m == 1) f = 2.f * wf2[k * HID + n] * (float)mask[k * HID + n];
        else             f = wtb[k * HID + n] - wta[k * HID + n];
      } else if (k == IN) {
        if (m == 0)      f = 2.f * bf1[n];
        else if (m == 1) f = 2.f * bf2[n];
        else             f = btb[n] - bta[n];
      }
      v[j] = (_Float16)f;
    }
  }
  *(f16x8*)(wt + (size_t)idx * 8) = v;
}

extern "C" void kernel_launch(void* const* d_in, const int* in_sizes, int n_in,
                              void* d_out, int out_size, void* d_ws, size_t ws_size,
                              hipStream_t stream)
{
  const float* x = (const float*)d_in[0];
  const float* Wf1_0 = (const float*)d_in[1];
  const float* bf1_0 = (const float*)d_in[2];
  const float* Wf2_0 = (const float*)d_in[3];
  const float* bf2_0 = (const float*)d_in[4];
  const float* Wta_0 = (const float*)d_in[5];
  const float* bta_0 = (const float*)d_in[6];
  const float* Wtb_0 = (const float*)d_in[7];
  const float* btb_0 = (const float*)d_in[8];
  const int*   msk_0 = (const int*)  d_in[9];
  const float* Wf1_1 = (const float*)d_in[10];
  const float* bf1_1 = (const float*)d_in[11];
  const float* Wf2_1 = (const float*)d_in[12];
  const float* bf2_1 = (const float*)d_in[13];
  const float* Wta_1 = (const float*)d_in[14];
  const float* bta_1 = (const float*)d_in[15];
  const float* Wtb_1 = (const float*)d_in[16];
  const float* btb_1 = (const float*)d_in[17];
  const int*   msk_1 = (const int*)  d_in[18];
  const float* Wf1_2 = (const float*)d_in[19];
  const float* bf1_2 = (const float*)d_in[20];
  const float* Wf2_2 = (const float*)d_in[21];
  const float* bf2_2 = (const float*)d_in[22];
  const float* Wta_2 = (const float*)d_in[23];
  const float* bta_2 = (const float*)d_in[24];
  const float* Wtb_2 = (const float*)d_in[25];
  const float* btb_2 = (const float*)d_in[26];
  const int*   msk_2 = (const int*)  d_in[27];

  char* ws = (char*)d_ws;
  _Float16* wt0 = (_Float16*)(ws + 0);        // 18*3*3*1024 = 165888
  _Float16* wt1 = (_Float16*)(ws + 165888);   // 12*9*3*1024 = 331776
  _Float16* wt2 = (_Float16*)(ws + 497664);   //  4*6*3*1024 =  73728

  pack_w<<<(18 * KS0 * 3 * 64 + 255) / 256, 256, 0, stream>>>(
      Wf1_0, Wf2_0, Wta_0, Wtb_0, bf1_0, bf2_0, bta_0, btb_0, msk_0, wt0, IN0, H0, KS0, 18);
  pack_w<<<(12 * KS1 * 3 * 64 + 255) / 256, 256, 0, stream>>>(
      Wf1_1, Wf2_1, Wta_1, Wtb_1, bf1_1, bf2_1, bta_1, btb_1, msk_1, wt1, H0, H1, KS1, 12);
  pack_w<<<( 4 * KS2 * 3 * 64 + 255) / 256, 256, 0, stream>>>(
      Wf1_2, Wf2_2, Wta_2, Wtb_2, bf1_2, bf2_2, bta_2, btb_2, msk_2, wt2, H1, H2, KS2, 4);

  cfc_fused<<<65536 / BM, 768, 0, stream>>>(x, wt0, wt1, wt2, (float*)d_out);
}